// Round 8
// baseline (493.119 us; speedup 1.0000x reference)
//
#include <hip/hip_runtime.h>
#include <hip/hip_bf16.h>

// Problem constants
#define Bb 256
#define Tt 256
#define Cc 384
#define Hh 6
#define Dd 64
#define Ww 64
#define Mm 128

typedef short short8 __attribute__((ext_vector_type(8)));
typedef float floatx4 __attribute__((ext_vector_type(4)));

static __device__ __forceinline__ unsigned short f2bf(float f) {
  union { __hip_bfloat16 h; unsigned short u; } cvt;
  cvt.h = __float2bfloat16(f);
  return cvt.u;
}

// async global->LDS, 16 bytes per lane. LDS dest is wave-uniform base + lane*16.
static __device__ __forceinline__ void gl2lds16(const unsigned short* g, unsigned short* l) {
  __builtin_amdgcn_global_load_lds(
      (const __attribute__((address_space(1))) unsigned int*)(const void*)g,
      (__attribute__((address_space(3))) unsigned int*)(void*)l,
      16, 0, 0);
}

#define VW(N) asm volatile("s_waitcnt vmcnt(" #N ")" ::: "memory")
#define BAR() __builtin_amdgcn_s_barrier()

// ---------------- conversion kernels ----------------

__global__ __launch_bounds__(256) void cvt_x(const float4* __restrict__ x,
                                             ushort4* __restrict__ xb) {
  size_t i = (size_t)blockIdx.x * 256 + threadIdx.x;
  float4 v = x[i];
  ushort4 o;
  o.x = f2bf(v.x); o.y = f2bf(v.y); o.z = f2bf(v.z); o.w = f2bf(v.w);
  xb[i] = o;
}

__global__ __launch_bounds__(256) void cvt_misc(const float* __restrict__ qkv_w,
                                                const float* __restrict__ proj_w,
                                                const float* __restrict__ mem,
                                                unsigned short* __restrict__ wb,
                                                unsigned short* __restrict__ pwb,
                                                unsigned short* __restrict__ memk,
                                                unsigned short* __restrict__ memvt) {
  int i = blockIdx.x * 256 + threadIdx.x;   // 0 .. 442367
  wb[i] = f2bf(qkv_w[i]);                   // 1152*384 = 442368 exact
  if (i < 147456) pwb[i] = f2bf(proj_w[i]); // 384*384
  if (i < 49152) {                          // memory 128*384
    int m = i / Cc, c = i % Cc, h = c >> 6, d = c & 63;
    unsigned short bv = f2bf(mem[i]);
    memk[(h * Mm + m) * Dd + d] = bv;       // [H][M][D]
    memvt[(h * Dd + d) * Mm + m] = bv;      // [H][D][M]
  }
}

// ---------------- GEMM 1: qkv = x @ qkv_w^T + b, scatter to q/k/vt ----------------
// R7 BARRIER-FREE PER-WAVE structure. Diagnosis from R2-R6: the invariant
// ceiling is the ds_read:MFMA ratio (1KB b128 ~12cyc vs MFMA 5cyc) plus
// barrier lockstep; R6's 2x2 acc (1 read/MFMA) sank to 13% MfmaUtil, 4x4
// (0.5 read/MFMA) rounds all stalled ~17% on barrier drains regardless of
// schedule. Fix: (1) A fragments load global->VGPR directly (no LDS, no
// barrier), 3-slot rotating prefetch 2 steps ahead (static idx, rule #20);
// (2) B strip (64 cols x 384 = 48KB) staged to LDS ONCE, then ZERO barriers:
// each wave runs its own 12-step K-loop; compiler's per-register counted
// waits are the only sync (per-wave, minimal). LDS 48KB -> 2 blocks/CU
// (16 waves/CU). Block 512thr = 8 waves x (64 rows x 64 cols, acc 4x4).
// B chunk-XOR swizzle (slot=(kc&0x38)|((kc&7)^(col&7))): 2-way-free b128.
// XCD map (d%8)*288+d/8: 18 col-strips of one 512-row panel adjacent on one
// XCD -> A panel (384KB) L2-hot, fetched once.

__global__ __launch_bounds__(512) void gemm_qkv(const unsigned short* __restrict__ xb,  // [65536][384]
                                                const unsigned short* __restrict__ wb,  // [1152][384]
                                                const float* __restrict__ qkv_b,        // [1152]
                                                unsigned short* __restrict__ q,   // [B,H,T,D] (prescaled)
                                                unsigned short* __restrict__ k,   // [B,H,T,D]
                                                unsigned short* __restrict__ vt)  // [B,H,D,T]
{
  int tid = threadIdx.x;
  int w = tid >> 6, lane = tid & 63, quad = lane >> 4, l16 = lane & 15;

  int id = blockIdx.y * 18 + blockIdx.x;           // 2304 blocks
  int orig = (id & 7) * 288 + (id >> 3);           // bijective, 2304 % 8 == 0
  int bx = orig % 18, by = orig / 18;
  int colbase = bx * 64;                           // 18 strips of 64 cols
  int rowbase = by * 512 + w * 64;                 // wave owns 64 rows

  // Bl: [64 cols][48 chunks of 16B, XOR-swizzled] = 48 KB
  __shared__ __align__(16) unsigned short Bl[24576];

  // ---- prologue A loads (k=0,1) — overlap B staging, no LDS involved ----
  short8 a[3][4];
#pragma unroll
  for (int rt = 0; rt < 4; ++rt)
    a[0][rt] = *reinterpret_cast<const short8*>(
        xb + (size_t)(rowbase + rt * 16 + l16) * 384 + 0 * 32 + quad * 8);
#pragma unroll
  for (int rt = 0; rt < 4; ++rt)
    a[1][rt] = *reinterpret_cast<const short8*>(
        xb + (size_t)(rowbase + rt * 16 + l16) * 384 + 1 * 32 + quad * 8);

  // ---- stage B strip once: 3072 chunks, 6/thread ----
#pragma unroll
  for (int i = 0; i < 6; ++i) {
    int G = i * 512 + tid;
    int col = G / 48, cs = G % 48;
    int c = (cs & 0x38) | ((cs & 7) ^ (col & 7));
    gl2lds16(wb + (size_t)(colbase + col) * 384 + c * 8, Bl + G * 8);
  }
  VW(0); BAR();    // the ONLY barrier in the kernel

  floatx4 acc[4][4] = {};

#define STEP_QKV(kk) do {                                                         \
    if ((kk) + 2 < 12) {                                                          \
      _Pragma("unroll")                                                           \
      for (int rt = 0; rt < 4; ++rt)                                              \
        a[((kk) + 2) % 3][rt] = *reinterpret_cast<const short8*>(                 \
            xb + (size_t)(rowbase + rt * 16 + l16) * 384 + ((kk) + 2) * 32 + quad * 8); \
    }                                                                             \
    short8 b[4];                                                                  \
    _Pragma("unroll")                                                             \
    for (int nt = 0; nt < 4; ++nt) {                                              \
      int kc = (kk) * 4 + quad;                                                   \
      int col = nt * 16 + l16;                                                    \
      int slot = (kc & 0x38) | ((kc & 7) ^ (col & 7));                            \
      b[nt] = *reinterpret_cast<const short8*>(&Bl[col * 384 + slot * 8]);        \
    }                                                                             \
    __builtin_amdgcn_s_setprio(1);                                                \
    _Pragma("unroll")                                                             \
    for (int rt = 0; rt < 4; ++rt)                                                \
      _Pragma("unroll")                                                           \
      for (int nt = 0; nt < 4; ++nt)                                              \
        acc[rt][nt] = __builtin_amdgcn_mfma_f32_16x16x32_bf16(a[(kk) % 3][rt],    \
                          b[nt], acc[rt][nt], 0, 0, 0);                           \
    __builtin_amdgcn_s_setprio(0);                                                \
  } while (0)

  STEP_QKV(0);  STEP_QKV(1);  STEP_QKV(2);  STEP_QKV(3);
  STEP_QKV(4);  STEP_QKV(5);  STEP_QKV(6);  STEP_QKV(7);
  STEP_QKV(8);  STEP_QKV(9);  STEP_QKV(10); STEP_QKV(11);
#undef STEP_QKV

#pragma unroll
  for (int nt = 0; nt < 4; ++nt) {
    int col = colbase + nt * 16 + l16;             // 0..1151
    int which = col >= 768 ? 2 : (col >= 384 ? 1 : 0);
    int cc = col - which * 384;
    int h = cc >> 6, d = cc & 63;
    float bias = qkv_b[col];
#pragma unroll
    for (int rt = 0; rt < 4; ++rt) {
#pragma unroll
      for (int r = 0; r < 4; ++r) {
        int row = rowbase + rt * 16 + quad * 4 + r;   // = b*T + t
        int bidx = row >> 8, tt = row & 255;
        float val = acc[rt][nt][r] + bias;
        size_t bh = (size_t)bidx * Hh + h;
        if (which == 0) {
          q[(bh * Tt + tt) * Dd + d] = f2bf(val * 0.125f);   // fold 1/sqrt(64)
        } else if (which == 1) {
          k[(bh * Tt + tt) * Dd + d] = f2bf(val);
        } else {
          vt[(bh * Dd + d) * Tt + tt] = f2bf(val);
        }
      }
    }
  }
}

// ---------------- Attention (LDS-staged, swizzled) ----------------
// grid (4, 6, 256) = (tq, h, b), block 256 = 4 waves; wave owns 16 query rows x 256 key cols.
// K/V staged ONCE per block via global_load_lds (was 4x redundant per-wave global loads).
// XOR chunk swizzle (slot = chunk ^ (row&7)) gives 2-way-free ds_read_b128 banking.
// LDS map (halfwords): [0,8192) Kmem | [8192,16384) Kwin | P reuses [0,16896) after
// barrier#2 | [16896,25088) Vmem | [25088,33280) Vwin. 66560 B -> 2 blocks/CU.
#define PSTRIDE 264   // hw; 528 B rows (16B-aligned), bank step 4 -> 2-way free

__global__ __launch_bounds__(256, 2) void attn(const unsigned short* __restrict__ q,
                                               const unsigned short* __restrict__ k,
                                               const unsigned short* __restrict__ vt,
                                               const unsigned short* __restrict__ memk,
                                               const unsigned short* __restrict__ memvt,
                                               const float* __restrict__ gate,
                                               unsigned short* __restrict__ aout) // [B,T,384] bf16
{
  int tq = blockIdx.x, h = blockIdx.y, b = blockIdx.z;
  int t0 = tq * 64;
  int tid = threadIdx.x, w = tid >> 6, lane = tid & 63, quad = lane >> 4, l16 = lane & 15;

  size_t bh = (size_t)b * Hh + h;
  const unsigned short* qp = q + (bh * Tt + t0 + w * 16) * Dd;
  const unsigned short* kp = k + bh * Tt * Dd;
  const unsigned short* vp = vt + bh * Dd * Tt;
  const unsigned short* mkp = memk + (size_t)h * Mm * Dd;
  const unsigned short* mvp = memvt + (size_t)h * Dd * Mm;

  __shared__ __align__(16) unsigned short lds[33280];
  unsigned short* Kmem = lds;            // [128 rows][8 chunks of 16B, swizzled]
  unsigned short* Kwin = lds + 8192;     // [128 rows][8 chunks]
  unsigned short* Pb   = lds;            // [4 waves][16 rows][PSTRIDE] after barrier#2
  unsigned short* Vmem = lds + 16896;    // [64 rows][16 chunks]
  unsigned short* Vwin = lds + 25088;    // [64 rows][16 chunks]
  unsigned short* pw = Pb + w * 16 * PSTRIDE;

  // Q fragments (A-operand): m=l16, k=quad*8+j — direct global (small, L2-hot)
  short8 qa[2];
#pragma unroll
  for (int ks = 0; ks < 2; ++ks)
    qa[ks] = *reinterpret_cast<const short8*>(qp + l16 * Dd + ks * 32 + quad * 8);

  // ---- async stage: K (mem+win) and V (mem+win), 16 DMA issues per thread ----
  // K regions: row r (128B = 8 chunks); stored chunk at slot cs holds chunk cs^(r&7).
#pragma unroll
  for (int i = 0; i < 4; ++i) {
    int G = (i * 4 + w) * 64;          // chunk group (64 chunks = 8 rows)
    int g = G + lane;
    int r = g >> 3, cs = g & 7;
    int c = cs ^ (r & 7);
    gl2lds16(mkp + r * 64 + c * 8, Kmem + G * 8 + lane * 8);
  }
#pragma unroll
  for (int i = 0; i < 4; ++i) {
    int G = (i * 4 + w) * 64;
    int g = G + lane;
    int r = g >> 3, cs = g & 7;
    int c = cs ^ (r & 7);
    int j = t0 - 64 + r;
    if (j < 0) j = 0;                  // branchless clamp; masked later
    gl2lds16(kp + (size_t)j * 64 + c * 8, Kwin + G * 8 + lane * 8);
  }
  // V regions: row d (128 cols = 16 chunks); slot cs holds chunk (cs&8)|((cs&7)^(d&7)).
#pragma unroll
  for (int i = 0; i < 4; ++i) {
    int G = (i * 4 + w) * 64;          // 64 chunks = 4 rows
    int g = G + lane;
    int d = g >> 4, cs = g & 15;
    int c = (cs & 8) | ((cs & 7) ^ (d & 7));
    gl2lds16(mvp + d * Mm + c * 8, Vmem + G * 8 + lane * 8);
  }
#pragma unroll
  for (int i = 0; i < 4; ++i) {
    int G = (i * 4 + w) * 64;
    int g = G + lane;
    int d = g >> 4, cs = g & 15;
    int c = (cs & 8) | ((cs & 7) ^ (d & 7));
    int j0 = t0 - 64 + c * 8;
    if (j0 < 0) j0 = 0;                // whole chunk below 0 -> P=0 there
    gl2lds16(vp + (size_t)d * Tt + j0, Vwin + G * 8 + lane * 8);
  }
  __syncthreads();   // drains vmcnt(0): all K/V staged

  floatx4 s[16] = {};

  // ---- QK^T memory tiles (cols 0..127): all valid ----
#pragma unroll
  for (int ct = 0; ct < 8; ++ct)
#pragma unroll
    for (int ks = 0; ks < 2; ++ks) {
      int slot = (ks * 4 + quad) ^ (l16 & 7);
      short8 bf = *reinterpret_cast<const short8*>(Kmem + (ct * 16 + l16) * 64 + slot * 8);
      s[ct] = __builtin_amdgcn_mfma_f32_16x16x32_bf16(qa[ks], bf, s[ct], 0, 0, 0);
    }
  // ---- QK^T window tiles: only ct' in [w, w+4] reachable (causal band) ----
#pragma unroll
  for (int ct = 0; ct < 8; ++ct) {
    if (ct >= w && ct <= w + 4) {
#pragma unroll
      for (int ks = 0; ks < 2; ++ks) {
        int slot = (ks * 4 + quad) ^ (l16 & 7);
        short8 bf = *reinterpret_cast<const short8*>(Kwin + (ct * 16 + l16) * 64 + slot * 8);
        s[8 + ct] = __builtin_amdgcn_mfma_f32_16x16x32_bf16(qa[ks], bf, s[8 + ct], 0, 0, 0);
      }
    }
  }
  __syncthreads();   // all waves done reading K region -> safe to overwrite with P

  // mask window tiles: valid iff 0 <= j <= i and i-j <= 64 (skipped tiles -> all -1e30)
#pragma unroll
  for (int ct = 8; ct < 16; ++ct) {
    int j = t0 - 64 + (ct - 8) * 16 + l16;
#pragma unroll
    for (int r = 0; r < 4; ++r) {
      int i = t0 + w * 16 + quad * 4 + r;
      bool valid = (j >= 0) && (j <= i) && (i - j <= 64);
      if (!valid) s[ct][r] = -1e30f;
    }
  }

  // softmax over 256 cols: rows live on 16 lanes of a quad -> intra-quad shuffles only
  float rm[4], rs[4], inv[4];
#pragma unroll
  for (int r = 0; r < 4; ++r) {
    float m = -1e30f;
#pragma unroll
    for (int ct = 0; ct < 16; ++ct) m = fmaxf(m, s[ct][r]);
    rm[r] = m;
  }
#pragma unroll
  for (int off = 1; off < 16; off <<= 1)
#pragma unroll
    for (int r = 0; r < 4; ++r) rm[r] = fmaxf(rm[r], __shfl_xor(rm[r], off, 64));
#pragma unroll
  for (int r = 0; r < 4; ++r) {
    float sum = 0.f;
#pragma unroll
    for (int ct = 0; ct < 16; ++ct) {
      float p = __expf(s[ct][r] - rm[r]);
      s[ct][r] = p;
      sum += p;
    }
    rs[r] = sum;
  }
#pragma unroll
  for (int off = 1; off < 16; off <<= 1)
#pragma unroll
    for (int r = 0; r < 4; ++r) rs[r] += __shfl_xor(rs[r], off, 64);
#pragma unroll
  for (int r = 0; r < 4; ++r) inv[r] = 1.0f / rs[r];

  // write P (bf16) to per-wave LDS region in [row][col] layout
#pragma unroll
  for (int ct = 0; ct < 16; ++ct)
#pragma unroll
    for (int r = 0; r < 4; ++r)
      pw[(quad * 4 + r) * PSTRIDE + ct * 16 + l16] = f2bf(s[ct][r]);

  // ---- PV memory chunks (cols 0..127) ----
  floatx4 o[4] = {};
#pragma unroll
  for (int ks = 0; ks < 4; ++ks) {
    short8 pa = *reinterpret_cast<const short8*>(pw + l16 * PSTRIDE + ks * 32 + quad * 8);
#pragma unroll
    for (int dt = 0; dt < 4; ++dt) {
      int c0 = ks * 4 + quad;
      int slot = (c0 & 8) | ((c0 & 7) ^ (l16 & 7));
      short8 vb = *reinterpret_cast<const short8*>(Vmem + (dt * 16 + l16) * 128 + slot * 8);
      o[dt] = __builtin_amdgcn_mfma_f32_16x16x32_bf16(pa, vb, o[dt], 0, 0, 0);
    }
  }
  // ---- PV window chunks: 3 of 4 reachable per wave ----
#pragma unroll
  for (int ks = 0; ks < 4; ++ks) {
    if (ks >= (w >> 1) && ks <= 2 + (w >> 1)) {
      short8 pa = *reinterpret_cast<const short8*>(pw + l16 * PSTRIDE + (4 + ks) * 32 + quad * 8);
#pragma unroll
      for (int dt = 0; dt < 4; ++dt) {
        int c0 = ks * 4 + quad;
        int slot = (c0 & 8) | ((c0 & 7) ^ (l16 & 7));
        short8 vb = *reinterpret_cast<const short8*>(Vwin + (dt * 16 + l16) * 128 + slot * 8);
        o[dt] = __builtin_amdgcn_mfma_f32_16x16x32_bf16(pa, vb, o[dt], 0, 0, 0);
      }
    }
  }

  // epilogue: normalize, gate, store bf16 row-major [b, t, c]
#pragma unroll
  for (int dt = 0; dt < 4; ++dt) {
    int c = h * 64 + dt * 16 + l16;
    float g = gate[c];
#pragma unroll
    for (int r = 0; r < 4; ++r) {
      int t = t0 + w * 16 + quad * 4 + r;
      float val = o[dt][r] * inv[r] * g;
      aout[((size_t)b * Tt + t) * Cc + c] = f2bf(val);
    }
  }
}

// ---------------- GEMM 2: out = aout @ proj_w^T + b, * loss_mask ----------------
// Same R7 barrier-free structure. N=384 -> 6 col strips of 64. grid (6,128)=768.

__global__ __launch_bounds__(512) void gemm_proj(const unsigned short* __restrict__ ab,  // [65536][384]
                                                 const unsigned short* __restrict__ pwb, // [384][384]
                                                 const float* __restrict__ proj_b,
                                                 const float* __restrict__ loss_mask,    // [65536]
                                                 float* __restrict__ out)                // [65536][384]
{
  int tid = threadIdx.x;
  int w = tid >> 6, lane = tid & 63, quad = lane >> 4, l16 = lane & 15;

  int id = blockIdx.y * 6 + blockIdx.x;            // 768 blocks
  int orig = (id & 7) * 96 + (id >> 3);            // bijective, 768 % 8 == 0
  int bx = orig % 6, by = orig / 6;
  int colbase = bx * 64;
  int rowbase = by * 512 + w * 64;

  __shared__ __align__(16) unsigned short Bl[24576];   // 48 KB

  short8 a[3][4];
#pragma unroll
  for (int rt = 0; rt < 4; ++rt)
    a[0][rt] = *reinterpret_cast<const short8*>(
        ab + (size_t)(rowbase + rt * 16 + l16) * 384 + 0 * 32 + quad * 8);
#pragma unroll
  for (int rt = 0; rt < 4; ++rt)
    a[1][rt] = *reinterpret_cast<const short8*>(
        ab + (size_t)(rowbase + rt * 16 + l16) * 384 + 1 * 32 + quad * 8);

#pragma unroll
  for (int i = 0; i < 6; ++i) {
    int G = i * 512 + tid;
    int col = G / 48, cs = G % 48;
    int c = (cs & 0x38) | ((cs & 7) ^ (col & 7));
    gl2lds16(pwb + (size_t)(colbase + col) * 384 + c * 8, Bl + G * 8);
  }
  VW(0); BAR();

  floatx4 acc[4][4] = {};

#define STEP_PROJ(kk) do {                                                        \
    if ((kk) + 2 < 12) {                                                          \
      _Pragma("unroll")                                                           \
      for (int rt = 0; rt < 4; ++rt)                                              \
        a[((kk) + 2) % 3][rt] = *reinterpret_cast<const short8*>(                 \
            ab + (size_t)(rowbase + rt * 16 + l16) * 384 + ((kk) + 2) * 32 + quad * 8); \
    }                                                                             \
    short8 b[4];                                                                  \
    _Pragma("unroll")                                                             \
    for (int nt = 0; nt < 4; ++nt) {                                              \
      int kc = (kk) * 4 + quad;                                                   \
      int col = nt * 16 + l16;                                                    \
      int slot = (kc & 0x38) | ((kc & 7) ^ (col & 7));                            \
      b[nt] = *reinterpret_cast<const short8*>(&Bl[col * 384 + slot * 8]);        \
    }                                                                             \
    __builtin_amdgcn_s_setprio(1);                                                \
    _Pragma("unroll")                                                             \
    for (int rt = 0; rt < 4; ++rt)                                                \
      _Pragma("unroll")                                                           \
      for (int nt = 0; nt < 4; ++nt)                                              \
        acc[rt][nt] = __builtin_amdgcn_mfma_f32_16x16x32_bf16(a[(kk) % 3][rt],    \
                          b[nt], acc[rt][nt], 0, 0, 0);                           \
    __builtin_amdgcn_s_setprio(0);                                                \
  } while (0)

  STEP_PROJ(0);  STEP_PROJ(1);  STEP_PROJ(2);  STEP_PROJ(3);
  STEP_PROJ(4);  STEP_PROJ(5);  STEP_PROJ(6);  STEP_PROJ(7);
  STEP_PROJ(8);  STEP_PROJ(9);  STEP_PROJ(10); STEP_PROJ(11);
#undef STEP_PROJ

#pragma unroll
  for (int nt = 0; nt < 4; ++nt) {
    int col = colbase + nt * 16 + l16;
    float bias = proj_b[col];
#pragma unroll
    for (int rt = 0; rt < 4; ++rt) {
#pragma unroll
      for (int r = 0; r < 4; ++r) {
        int row = rowbase + rt * 16 + quad * 4 + r;
        float val = (acc[rt][nt][r] + bias) * loss_mask[row];
        out[(size_t)row * 384 + col] = val;
      }
    }
  }
}

// ---------------- launcher ----------------

extern "C" void kernel_launch(void* const* d_in, const int* in_sizes, int n_in,
                              void* d_out, int out_size, void* d_ws, size_t ws_size,
                              hipStream_t stream) {
  const float* x = (const float*)d_in[0];
  const float* memory = (const float*)d_in[1];
  const float* loss_mask = (const float*)d_in[2];
  const float* qkv_w = (const float*)d_in[3];
  const float* qkv_b = (const float*)d_in[4];
  const float* proj_w = (const float*)d_in[5];
  const float* proj_b = (const float*)d_in[6];
  const float* gate = (const float*)d_in[7];
  float* out = (float*)d_out;

  char* ws = (char*)d_ws;
  // byte offsets (all 16B aligned). xb is reused as aout (dead after gemm_qkv).
  unsigned short* xb    = (unsigned short*)(ws + 0);            // 50,331,648 B
  unsigned short* qb    = (unsigned short*)(ws + 50331648);     // 50,331,648 B
  unsigned short* kb    = (unsigned short*)(ws + 100663296);    // 50,331,648 B
  unsigned short* vtb   = (unsigned short*)(ws + 150994944);    // 50,331,648 B
  unsigned short* wb    = (unsigned short*)(ws + 201326592);    //    884,736 B
  unsigned short* pwb   = (unsigned short*)(ws + 202211328);    //    294,912 B
  unsigned short* memk  = (unsigned short*)(ws + 202506240);    //     98,304 B
  unsigned short* memvt = (unsigned short*)(ws + 202604544);    //     98,304 B
  unsigned short* aout  = xb;

  cvt_x<<<dim3(24576), dim3(256), 0, stream>>>((const float4*)x, (ushort4*)xb);
  cvt_misc<<<dim3(1728), dim3(256), 0, stream>>>(qkv_w, proj_w, memory, wb, pwb, memk, memvt);
  gemm_qkv<<<dim3(18, 128), dim3(512), 0, stream>>>(xb, wb, qkv_b, qb, kb, vtb);
  attn<<<dim3(4, 6, 256), dim3(256), 0, stream>>>(qb, kb, vtb, memk, memvt, gate, aout);
  gemm_proj<<<dim3(6, 128), dim3(512), 0, stream>>>(aout, pwb, proj_b, loss_mask, out);
}

// Round 9
// 417.232 us; speedup vs baseline: 1.1819x; 1.1819x over previous
//
#include <hip/hip_runtime.h>
#include <hip/hip_bf16.h>

// Problem constants
#define Bb 256
#define Tt 256
#define Cc 384
#define Hh 6
#define Dd 64
#define Ww 64
#define Mm 128

typedef short short8 __attribute__((ext_vector_type(8)));
typedef float floatx4 __attribute__((ext_vector_type(4)));

static __device__ __forceinline__ unsigned short f2bf(float f) {
  union { __hip_bfloat16 h; unsigned short u; } cvt;
  cvt.h = __float2bfloat16(f);
  return cvt.u;
}

// async global->LDS, 16 bytes per lane. LDS dest is wave-uniform base + lane*16.
static __device__ __forceinline__ void gl2lds16(const unsigned short* g, unsigned short* l) {
  __builtin_amdgcn_global_load_lds(
      (const __attribute__((address_space(1))) unsigned int*)(const void*)g,
      (__attribute__((address_space(3))) unsigned int*)(void*)l,
      16, 0, 0);
}

// counted waits + raw barrier (T4): never drain vmcnt(0) in the main loop.
#define VW(N) asm volatile("s_waitcnt vmcnt(" #N ")" ::: "memory")
#define BAR() __builtin_amdgcn_s_barrier()

// ---------------- conversion kernel (merged cvt_x + cvt_misc) ----------------
// All blocks convert x (float4 -> ushort4). The first 1728 blocks additionally
// convert qkv_w/proj_w/memory (they carry 2x work; 7% of the grid, scheduler
// absorbs it). One launch instead of two.

__global__ __launch_bounds__(256) void cvt_all(const float4* __restrict__ x,
                                               ushort4* __restrict__ xb,
                                               const float* __restrict__ qkv_w,
                                               const float* __restrict__ proj_w,
                                               const float* __restrict__ mem,
                                               unsigned short* __restrict__ wb,
                                               unsigned short* __restrict__ pwb,
                                               unsigned short* __restrict__ memk,
                                               unsigned short* __restrict__ memvt) {
  size_t i = (size_t)blockIdx.x * 256 + threadIdx.x;
  float4 v = x[i];
  ushort4 o;
  o.x = f2bf(v.x); o.y = f2bf(v.y); o.z = f2bf(v.z); o.w = f2bf(v.w);
  xb[i] = o;

  if (blockIdx.x < 1728) {
    int j = blockIdx.x * 256 + threadIdx.x;   // 0 .. 442367
    wb[j] = f2bf(qkv_w[j]);                   // 1152*384 = 442368 exact
    if (j < 147456) pwb[j] = f2bf(proj_w[j]); // 384*384
    if (j < 49152) {                          // memory 128*384
      int m = j / Cc, c = j % Cc, h = c >> 6, d = c & 63;
      unsigned short bv = f2bf(mem[j]);
      memk[(h * Mm + m) * Dd + d] = bv;       // [H][M][D]
      memvt[(h * Dd + d) * Mm + m] = bv;      // [H][D][M]
    }
  }
}

// ---------------- GEMM 1: qkv = x @ qkv_w^T + b, scatter to q/k/vt ----------------
// R4-EXACT structure (measured session-best: 137.3 us, MfmaUtil 17.3%,
// SQ_LDS_BANK_CONFLICT 0). BM=BN=128, BK=64, 4 waves. Counted-vmcnt 2-buffer
// pipeline: stage 8 DMA/buffer, 16 in flight, s_waitcnt vmcnt(8) retires
// exactly the older buffer, raw s_barrier (no compiler vmcnt(0) drain).
// LDS tile [128 rows][64hw=8 chunks], chunk XOR (row&7) swizzle via
// pre-swizzled GLOBAL source + same XOR on ds_read slot: conflict-free b128.
// LDS 64 KB -> 2 blocks/CU. XCD-bijective swizzle: 4608 % 8 == 0, 576/XCD;
// within an XCD blocks run col-fastest over 9 col-strips -> A strip L2-hot.
// NOTE (R5-R7 post-mortems): 3-buf deeper pipeline, B-resident mega-tiles,
// and barrier-free per-wave variants ALL regressed (202/183/196 us) — this
// structure is the empirical floor of the family; do not churn it further.

__global__ __launch_bounds__(256) void gemm_qkv(const unsigned short* __restrict__ xb,  // [65536][384]
                                                const unsigned short* __restrict__ wb,  // [1152][384]
                                                const float* __restrict__ qkv_b,        // [1152]
                                                unsigned short* __restrict__ q,   // [B,H,T,D] (prescaled)
                                                unsigned short* __restrict__ k,   // [B,H,T,D]
                                                unsigned short* __restrict__ vt)  // [B,H,D,T]
{
  int tid = threadIdx.x;
  int w = tid >> 6, lane = tid & 63, quad = lane >> 4, l16 = lane & 15;

  int orig = blockIdx.y * 9 + blockIdx.x;
  int newid = (orig & 7) * 576 + (orig >> 3);   // bijective, 4608 % 8 == 0
  int bx = newid % 9, by = newid / 9;

  int rowbase = by * 128;
  int colbase = bx * 128;
  int rowofs = (w >> 1) * 64, colofs = (w & 1) * 64;

  // [2 buf][128 rows][64 hw = 8 chunks of 16B], chunk slot cs holds chunk cs^(r&7)
  __shared__ __align__(16) unsigned short Alds[2][128 * 64];   // 32 KB
  __shared__ __align__(16) unsigned short Blds[2][128 * 64];   // 32 KB

  // stage: 1024 chunks per tile, 256 thr x 4; g = chunk id, r = g>>3, slot = g&7
#define STAGE_QKV(buf, s_) do {                                                   \
    int kk = (s_) * 64;                                                           \
    _Pragma("unroll")                                                             \
    for (int i = 0; i < 4; ++i) {                                                 \
      int g = (i * 4 + w) * 64 + lane;                                            \
      int r = g >> 3, cs = g & 7, c = cs ^ (r & 7);                               \
      gl2lds16(xb + (size_t)(rowbase + r) * 384 + kk + c * 8,                     \
               &Alds[buf][g * 8]);                                                \
      gl2lds16(wb + (size_t)(colbase + r) * 384 + kk + c * 8,                     \
               &Blds[buf][g * 8]);                                                \
    }                                                                             \
  } while (0)

  // compute: per ks half (K=32), frag k-chunk q = ks*4+quad, slot = q^(l16&7)
#define COMPUTE_QKV(buf) do {                                                     \
    __builtin_amdgcn_s_setprio(1);                                                \
    _Pragma("unroll")                                                             \
    for (int ks = 0; ks < 2; ++ks) {                                              \
      short8 a[4], b[4];                                                          \
      int slot = ((ks * 4 + quad) ^ (l16 & 7)) * 8;                               \
      _Pragma("unroll")                                                           \
      for (int rt = 0; rt < 4; ++rt)                                              \
        a[rt] = *reinterpret_cast<const short8*>(                                 \
            &Alds[buf][(rowofs + rt * 16 + l16) * 64 + slot]);                    \
      _Pragma("unroll")                                                           \
      for (int nt = 0; nt < 4; ++nt)                                              \
        b[nt] = *reinterpret_cast<const short8*>(                                 \
            &Blds[buf][(colofs + nt * 16 + l16) * 64 + slot]);                    \
      _Pragma("unroll")                                                           \
      for (int rt = 0; rt < 4; ++rt)                                              \
        _Pragma("unroll")                                                         \
        for (int nt = 0; nt < 4; ++nt)                                            \
          acc[rt][nt] = __builtin_amdgcn_mfma_f32_16x16x32_bf16(a[rt], b[nt],     \
                                                                acc[rt][nt], 0, 0, 0); \
    }                                                                             \
    __builtin_amdgcn_s_setprio(0);                                                \
  } while (0)

  floatx4 acc[4][4] = {};
  // K = 384 = 6 steps of 64. 8 DMA per STAGE; vmcnt(8) = older stage retired.
  STAGE_QKV(0, 0);
  STAGE_QKV(1, 1);
  VW(8); BAR();        // buf0 ready (all waves)
  COMPUTE_QKV(0);
  BAR();               // all reads of buf0 done
  STAGE_QKV(0, 2);
  VW(8); BAR();        // buf1 ready
  COMPUTE_QKV(1);
  BAR();
  STAGE_QKV(1, 3);
  VW(8); BAR();        // buf0 ready
  COMPUTE_QKV(0);
  BAR();
  STAGE_QKV(0, 4);
  VW(8); BAR();        // buf1 ready
  COMPUTE_QKV(1);
  BAR();
  STAGE_QKV(1, 5);
  VW(8); BAR();        // buf0 ready
  COMPUTE_QKV(0);
  VW(0); BAR();        // drain buf1's stage
  COMPUTE_QKV(1);

#pragma unroll
  for (int nt = 0; nt < 4; ++nt) {
    int col = colbase + colofs + nt * 16 + l16;    // 0..1151
    int which = col >= 768 ? 2 : (col >= 384 ? 1 : 0);
    int cc = col - which * 384;
    int h = cc >> 6, d = cc & 63;
    float bias = qkv_b[col];
#pragma unroll
    for (int rt = 0; rt < 4; ++rt) {
#pragma unroll
      for (int r = 0; r < 4; ++r) {
        int row = rowbase + rowofs + rt * 16 + quad * 4 + r;   // = b*T + t
        int bidx = row >> 8, t = row & 255;
        float val = acc[rt][nt][r] + bias;
        size_t bh = (size_t)bidx * Hh + h;
        if (which == 0) {
          q[(bh * Tt + t) * Dd + d] = f2bf(val * 0.125f);   // fold 1/sqrt(64)
        } else if (which == 1) {
          k[(bh * Tt + t) * Dd + d] = f2bf(val);
        } else {
          vt[(bh * Dd + d) * Tt + t] = f2bf(val);
        }
      }
    }
  }
#undef STAGE_QKV
#undef COMPUTE_QKV
}

// ---------------- Attention (LDS-staged, swizzled) ----------------
// grid (4, 6, 256) = (tq, h, b), block 256 = 4 waves; wave owns 16 query rows x 256 key cols.
// K/V staged ONCE per block via global_load_lds (was 4x redundant per-wave global loads).
// XOR chunk swizzle (slot = chunk ^ (row&7)) gives 2-way-free ds_read_b128 banking.
// LDS map (halfwords): [0,8192) Kmem | [8192,16384) Kwin | P reuses [0,16896) after
// barrier#2 | [16896,25088) Vmem | [25088,33280) Vwin. 66560 B -> 2 blocks/CU.
#define PSTRIDE 264   // hw; 528 B rows (16B-aligned), bank step 4 -> 2-way free

__global__ __launch_bounds__(256, 2) void attn(const unsigned short* __restrict__ q,
                                               const unsigned short* __restrict__ k,
                                               const unsigned short* __restrict__ vt,
                                               const unsigned short* __restrict__ memk,
                                               const unsigned short* __restrict__ memvt,
                                               const float* __restrict__ gate,
                                               unsigned short* __restrict__ aout) // [B,T,384] bf16
{
  int tq = blockIdx.x, h = blockIdx.y, b = blockIdx.z;
  int t0 = tq * 64;
  int tid = threadIdx.x, w = tid >> 6, lane = tid & 63, quad = lane >> 4, l16 = lane & 15;

  size_t bh = (size_t)b * Hh + h;
  const unsigned short* qp = q + (bh * Tt + t0 + w * 16) * Dd;
  const unsigned short* kp = k + bh * Tt * Dd;
  const unsigned short* vp = vt + bh * Dd * Tt;
  const unsigned short* mkp = memk + (size_t)h * Mm * Dd;
  const unsigned short* mvp = memvt + (size_t)h * Dd * Mm;

  __shared__ __align__(16) unsigned short lds[33280];
  unsigned short* Kmem = lds;            // [128 rows][8 chunks of 16B, swizzled]
  unsigned short* Kwin = lds + 8192;     // [128 rows][8 chunks]
  unsigned short* Pb   = lds;            // [4 waves][16 rows][PSTRIDE] after barrier#2
  unsigned short* Vmem = lds + 16896;    // [64 rows][16 chunks]
  unsigned short* Vwin = lds + 25088;    // [64 rows][16 chunks]
  unsigned short* pw = Pb + w * 16 * PSTRIDE;

  // Q fragments (A-operand): m=l16, k=quad*8+j — direct global (small, L2-hot)
  short8 qa[2];
#pragma unroll
  for (int ks = 0; ks < 2; ++ks)
    qa[ks] = *reinterpret_cast<const short8*>(qp + l16 * Dd + ks * 32 + quad * 8);

  // ---- async stage: K (mem+win) and V (mem+win), 16 DMA issues per thread ----
  // K regions: row r (128B = 8 chunks); stored chunk at slot cs holds chunk cs^(r&7).
#pragma unroll
  for (int i = 0; i < 4; ++i) {
    int G = (i * 4 + w) * 64;          // chunk group (64 chunks = 8 rows)
    int g = G + lane;
    int r = g >> 3, cs = g & 7;
    int c = cs ^ (r & 7);
    gl2lds16(mkp + r * 64 + c * 8, Kmem + G * 8 + lane * 8);
  }
#pragma unroll
  for (int i = 0; i < 4; ++i) {
    int G = (i * 4 + w) * 64;
    int g = G + lane;
    int r = g >> 3, cs = g & 7;
    int c = cs ^ (r & 7);
    int j = t0 - 64 + r;
    if (j < 0) j = 0;                  // branchless clamp; masked later
    gl2lds16(kp + (size_t)j * 64 + c * 8, Kwin + G * 8 + lane * 8);
  }
  // V regions: row d (128 cols = 16 chunks); slot cs holds chunk (cs&8)|((cs&7)^(d&7)).
#pragma unroll
  for (int i = 0; i < 4; ++i) {
    int G = (i * 4 + w) * 64;          // 64 chunks = 4 rows
    int g = G + lane;
    int d = g >> 4, cs = g & 15;
    int c = (cs & 8) | ((cs & 7) ^ (d & 7));
    gl2lds16(mvp + d * Mm + c * 8, Vmem + G * 8 + lane * 8);
  }
#pragma unroll
  for (int i = 0; i < 4; ++i) {
    int G = (i * 4 + w) * 64;
    int g = G + lane;
    int d = g >> 4, cs = g & 15;
    int c = (cs & 8) | ((cs & 7) ^ (d & 7));
    int j0 = t0 - 64 + c * 8;
    if (j0 < 0) j0 = 0;                // whole chunk below 0 -> P=0 there
    gl2lds16(vp + (size_t)d * Tt + j0, Vwin + G * 8 + lane * 8);
  }
  __syncthreads();   // drains vmcnt(0): all K/V staged

  floatx4 s[16] = {};

  // ---- QK^T memory tiles (cols 0..127): all valid ----
#pragma unroll
  for (int ct = 0; ct < 8; ++ct)
#pragma unroll
    for (int ks = 0; ks < 2; ++ks) {
      int slot = (ks * 4 + quad) ^ (l16 & 7);
      short8 bf = *reinterpret_cast<const short8*>(Kmem + (ct * 16 + l16) * 64 + slot * 8);
      s[ct] = __builtin_amdgcn_mfma_f32_16x16x32_bf16(qa[ks], bf, s[ct], 0, 0, 0);
    }
  // ---- QK^T window tiles: only ct' in [w, w+4] reachable (causal band) ----
#pragma unroll
  for (int ct = 0; ct < 8; ++ct) {
    if (ct >= w && ct <= w + 4) {
#pragma unroll
      for (int ks = 0; ks < 2; ++ks) {
        int slot = (ks * 4 + quad) ^ (l16 & 7);
        short8 bf = *reinterpret_cast<const short8*>(Kwin + (ct * 16 + l16) * 64 + slot * 8);
        s[8 + ct] = __builtin_amdgcn_mfma_f32_16x16x32_bf16(qa[ks], bf, s[8 + ct], 0, 0, 0);
      }
    }
  }
  __syncthreads();   // all waves done reading K region -> safe to overwrite with P

  // mask window tiles: valid iff 0 <= j <= i and i-j <= 64 (skipped tiles -> all -1e30)
#pragma unroll
  for (int ct = 8; ct < 16; ++ct) {
    int j = t0 - 64 + (ct - 8) * 16 + l16;
#pragma unroll
    for (int r = 0; r < 4; ++r) {
      int i = t0 + w * 16 + quad * 4 + r;
      bool valid = (j >= 0) && (j <= i) && (i - j <= 64);
      if (!valid) s[ct][r] = -1e30f;
    }
  }

  // softmax over 256 cols: rows live on 16 lanes of a quad -> intra-quad shuffles only
  float rm[4], rs[4], inv[4];
#pragma unroll
  for (int r = 0; r < 4; ++r) {
    float m = -1e30f;
#pragma unroll
    for (int ct = 0; ct < 16; ++ct) m = fmaxf(m, s[ct][r]);
    rm[r] = m;
  }
#pragma unroll
  for (int off = 1; off < 16; off <<= 1)
#pragma unroll
    for (int r = 0; r < 4; ++r) rm[r] = fmaxf(rm[r], __shfl_xor(rm[r], off, 64));
#pragma unroll
  for (int r = 0; r < 4; ++r) {
    float sum = 0.f;
#pragma unroll
    for (int ct = 0; ct < 16; ++ct) {
      float p = __expf(s[ct][r] - rm[r]);
      s[ct][r] = p;
      sum += p;
    }
    rs[r] = sum;
  }
#pragma unroll
  for (int off = 1; off < 16; off <<= 1)
#pragma unroll
    for (int r = 0; r < 4; ++r) rs[r] += __shfl_xor(rs[r], off, 64);
#pragma unroll
  for (int r = 0; r < 4; ++r) inv[r] = 1.0f / rs[r];

  // write P (bf16) to per-wave LDS region in [row][col] layout
#pragma unroll
  for (int ct = 0; ct < 16; ++ct)
#pragma unroll
    for (int r = 0; r < 4; ++r)
      pw[(quad * 4 + r) * PSTRIDE + ct * 16 + l16] = f2bf(s[ct][r]);

  // ---- PV memory chunks (cols 0..127) ----
  floatx4 o[4] = {};
#pragma unroll
  for (int ks = 0; ks < 4; ++ks) {
    short8 pa = *reinterpret_cast<const short8*>(pw + l16 * PSTRIDE + ks * 32 + quad * 8);
#pragma unroll
    for (int dt = 0; dt < 4; ++dt) {
      int c0 = ks * 4 + quad;
      int slot = (c0 & 8) | ((c0 & 7) ^ (l16 & 7));
      short8 vb = *reinterpret_cast<const short8*>(Vmem + (dt * 16 + l16) * 128 + slot * 8);
      o[dt] = __builtin_amdgcn_mfma_f32_16x16x32_bf16(pa, vb, o[dt], 0, 0, 0);
    }
  }
  // ---- PV window chunks: 3 of 4 reachable per wave ----
#pragma unroll
  for (int ks = 0; ks < 4; ++ks) {
    if (ks >= (w >> 1) && ks <= 2 + (w >> 1)) {
      short8 pa = *reinterpret_cast<const short8*>(pw + l16 * PSTRIDE + (4 + ks) * 32 + quad * 8);
#pragma unroll
      for (int dt = 0; dt < 4; ++dt) {
        int c0 = ks * 4 + quad;
        int slot = (c0 & 8) | ((c0 & 7) ^ (l16 & 7));
        short8 vb = *reinterpret_cast<const short8*>(Vwin + (dt * 16 + l16) * 128 + slot * 8);
        o[dt] = __builtin_amdgcn_mfma_f32_16x16x32_bf16(pa, vb, o[dt], 0, 0, 0);
      }
    }
  }

  // epilogue: normalize, gate, store bf16 row-major [b, t, c]
#pragma unroll
  for (int dt = 0; dt < 4; ++dt) {
    int c = h * 64 + dt * 16 + l16;
    float g = gate[c];
#pragma unroll
    for (int r = 0; r < 4; ++r) {
      int t = t0 + w * 16 + quad * 4 + r;
      float val = o[dt][r] * inv[r] * g;
      aout[((size_t)b * Tt + t) * Cc + c] = f2bf(val);
    }
  }
}

// ---------------- GEMM 2: out = aout @ proj_w^T + b, * loss_mask ----------------
// R4-exact structure: BK=64 XOR-swizzled tiles + counted-vmcnt pipeline.
// grid (3,512)=1536 blocks, XCD swizzle 192/XCD.

__global__ __launch_bounds__(256) void gemm_proj(const unsigned short* __restrict__ ab,  // [65536][384]
                                                 const unsigned short* __restrict__ pwb, // [384][384]
                                                 const float* __restrict__ proj_b,
                                                 const float* __restrict__ loss_mask,    // [65536]
                                                 float* __restrict__ out)                // [65536][384]
{
  int tid = threadIdx.x;
  int w = tid >> 6, lane = tid & 63, quad = lane >> 4, l16 = lane & 15;

  int orig = blockIdx.y * 3 + blockIdx.x;
  int newid = (orig & 7) * 192 + (orig >> 3);   // bijective, 1536 % 8 == 0
  int bx = newid % 3, by = newid / 3;

  int rowbase = by * 128;
  int colbase = bx * 128;
  int rowofs = (w >> 1) * 64, colofs = (w & 1) * 64;

  __shared__ __align__(16) unsigned short Alds[2][128 * 64];
  __shared__ __align__(16) unsigned short Blds[2][128 * 64];

#define STAGE_PROJ(buf, s_) do {                                                  \
    int kk = (s_) * 64;                                                           \
    _Pragma("unroll")                                                             \
    for (int i = 0; i < 4; ++i) {                                                 \
      int g = (i * 4 + w) * 64 + lane;                                            \
      int r = g >> 3, cs = g & 7, c = cs ^ (r & 7);                               \
      gl2lds16(ab + (size_t)(rowbase + r) * 384 + kk + c * 8,                     \
               &Alds[buf][g * 8]);                                                \
      gl2lds16(pwb + (size_t)(colbase + r) * 384 + kk + c * 8,                    \
               &Blds[buf][g * 8]);                                                \
    }                                                                             \
  } while (0)

#define COMPUTE_PROJ(buf) do {                                                    \
    __builtin_amdgcn_s_setprio(1);                                                \
    _Pragma("unroll")                                                             \
    for (int ks = 0; ks < 2; ++ks) {                                              \
      short8 a[4], b[4];                                                          \
      int slot = ((ks * 4 + quad) ^ (l16 & 7)) * 8;                               \
      _Pragma("unroll")                                                           \
      for (int rt = 0; rt < 4; ++rt)                                              \
        a[rt] = *reinterpret_cast<const short8*>(                                 \
            &Alds[buf][(rowofs + rt * 16 + l16) * 64 + slot]);                    \
      _Pragma("unroll")                                                           \
      for (int nt = 0; nt < 4; ++nt)                                              \
        b[nt] = *reinterpret_cast<const short8*>(                                 \
            &Blds[buf][(colofs + nt * 16 + l16) * 64 + slot]);                    \
      _Pragma("unroll")                                                           \
      for (int rt = 0; rt < 4; ++rt)                                              \
        _Pragma("unroll")                                                         \
        for (int nt = 0; nt < 4; ++nt)                                            \
          acc[rt][nt] = __builtin_amdgcn_mfma_f32_16x16x32_bf16(a[rt], b[nt],     \
                                                                acc[rt][nt], 0, 0, 0); \
    }                                                                             \
    __builtin_amdgcn_s_setprio(0);                                                \
  } while (0)

  floatx4 acc[4][4] = {};
  STAGE_PROJ(0, 0);
  STAGE_PROJ(1, 1);
  VW(8); BAR();
  COMPUTE_PROJ(0);
  BAR();
  STAGE_PROJ(0, 2);
  VW(8); BAR();
  COMPUTE_PROJ(1);
  BAR();
  STAGE_PROJ(1, 3);
  VW(8); BAR();
  COMPUTE_PROJ(0);
  BAR();
  STAGE_PROJ(0, 4);
  VW(8); BAR();
  COMPUTE_PROJ(1);
  BAR();
  STAGE_PROJ(1, 5);
  VW(8); BAR();
  COMPUTE_PROJ(0);
  VW(0); BAR();
  COMPUTE_PROJ(1);

#pragma unroll
  for (int nt = 0; nt < 4; ++nt) {
    int col = colbase + colofs + nt * 16 + l16;
    float bias = proj_b[col];
#pragma unroll
    for (int rt = 0; rt < 4; ++rt) {
#pragma unroll
      for (int r = 0; r < 4; ++r) {
        int row = rowbase + rowofs + rt * 16 + quad * 4 + r;
        float val = (acc[rt][nt][r] + bias) * loss_mask[row];
        out[(size_t)row * 384 + col] = val;
      }
    }
  }
#undef STAGE_PROJ
#undef COMPUTE_PROJ
}

// ---------------- launcher ----------------

extern "C" void kernel_launch(void* const* d_in, const int* in_sizes, int n_in,
                              void* d_out, int out_size, void* d_ws, size_t ws_size,
                              hipStream_t stream) {
  const float* x = (const float*)d_in[0];
  const float* memory = (const float*)d_in[1];
  const float* loss_mask = (const float*)d_in[2];
  const float* qkv_w = (const float*)d_in[3];
  const float* qkv_b = (const float*)d_in[4];
  const float* proj_w = (const float*)d_in[5];
  const float* proj_b = (const float*)d_in[6];
  const float* gate = (const float*)d_in[7];
  float* out = (float*)d_out;

  char* ws = (char*)d_ws;
  // byte offsets (all 16B aligned). xb is reused as aout (dead after gemm_qkv).
  unsigned short* xb    = (unsigned short*)(ws + 0);            // 50,331,648 B
  unsigned short* qb    = (unsigned short*)(ws + 50331648);     // 50,331,648 B
  unsigned short* kb    = (unsigned short*)(ws + 100663296);    // 50,331,648 B
  unsigned short* vtb   = (unsigned short*)(ws + 150994944);    // 50,331,648 B
  unsigned short* wb    = (unsigned short*)(ws + 201326592);    //    884,736 B
  unsigned short* pwb   = (unsigned short*)(ws + 202211328);    //    294,912 B
  unsigned short* memk  = (unsigned short*)(ws + 202506240);    //     98,304 B
  unsigned short* memvt = (unsigned short*)(ws + 202604544);    //     98,304 B
  unsigned short* aout  = xb;

  cvt_all<<<dim3(24576), dim3(256), 0, stream>>>((const float4*)x, (ushort4*)xb,
                                                 qkv_w, proj_w, memory, wb, pwb, memk, memvt);
  gemm_qkv<<<dim3(9, 512), dim3(256), 0, stream>>>(xb, wb, qkv_b, qb, kb, vtb);
  attn<<<dim3(4, 6, 256), dim3(256), 0, stream>>>(qb, kb, vtb, memk, memvt, gate, aout);
  gemm_proj<<<dim3(3, 512), dim3(256), 0, stream>>>(aout, pwb, proj_b, loss_mask, out);
}